// Round 1
// baseline (599.440 us; speedup 1.0000x reference)
//
#include <hip/hip_runtime.h>
#include <cstdint>
#include <cstddef>

// Problem constants
#define T_TOK 8192    // B*S tokens
#define DM    2048    // d_model
#define DI    4096    // d_inner
#define TWO_DI 8192

typedef __attribute__((ext_vector_type(8))) short bf16x8;
typedef __attribute__((ext_vector_type(4))) float f32x4;

__device__ __forceinline__ unsigned short f2bf(float f) {
  union { float f; unsigned u; } c; c.f = f;
  unsigned u = c.u;
  unsigned r = (u + 0x7fffu + ((u >> 16) & 1u)) >> 16;  // RNE
  return (unsigned short)r;
}

// ---------------------------------------------------------------------------
// LayerNorm over last dim (2048) + cast to bf16. One block per token.
// ---------------------------------------------------------------------------
__global__ __launch_bounds__(256) void ln_kernel(
    const float* __restrict__ x, const float* __restrict__ gamma,
    const float* __restrict__ beta, unsigned short* __restrict__ xn) {
  const int t = blockIdx.x;
  const int tid = threadIdx.x;
  const float* row = x + (size_t)t * DM;
  float4 v0 = reinterpret_cast<const float4*>(row)[tid];
  float4 v1 = reinterpret_cast<const float4*>(row)[tid + 256];
  float s  = v0.x + v0.y + v0.z + v0.w + v1.x + v1.y + v1.z + v1.w;
  float ss = v0.x*v0.x + v0.y*v0.y + v0.z*v0.z + v0.w*v0.w
           + v1.x*v1.x + v1.y*v1.y + v1.z*v1.z + v1.w*v1.w;
  #pragma unroll
  for (int off = 32; off > 0; off >>= 1) {
    s  += __shfl_down(s, off);
    ss += __shfl_down(ss, off);
  }
  __shared__ float red[8];
  __shared__ float mu_s, inv_s;
  if ((tid & 63) == 0) { red[tid >> 6] = s; red[4 + (tid >> 6)] = ss; }
  __syncthreads();
  if (tid == 0) {
    float S  = red[0] + red[1] + red[2] + red[3];
    float SS = red[4] + red[5] + red[6] + red[7];
    float mu  = S * (1.0f / DM);
    float var = SS * (1.0f / DM) - mu * mu;
    mu_s = mu;
    inv_s = rsqrtf(var + 1e-5f);
  }
  __syncthreads();
  const float mu = mu_s, inv = inv_s;
  float4 g0 = reinterpret_cast<const float4*>(gamma)[tid];
  float4 b0 = reinterpret_cast<const float4*>(beta)[tid];
  float4 g1 = reinterpret_cast<const float4*>(gamma)[tid + 256];
  float4 b1 = reinterpret_cast<const float4*>(beta)[tid + 256];
  ushort4 o0, o1;
  o0.x = f2bf((v0.x - mu) * inv * g0.x + b0.x);
  o0.y = f2bf((v0.y - mu) * inv * g0.y + b0.y);
  o0.z = f2bf((v0.z - mu) * inv * g0.z + b0.z);
  o0.w = f2bf((v0.w - mu) * inv * g0.w + b0.w);
  o1.x = f2bf((v1.x - mu) * inv * g1.x + b1.x);
  o1.y = f2bf((v1.y - mu) * inv * g1.y + b1.y);
  o1.z = f2bf((v1.z - mu) * inv * g1.z + b1.z);
  o1.w = f2bf((v1.w - mu) * inv * g1.w + b1.w);
  reinterpret_cast<ushort4*>(xn + (size_t)t * DM)[tid]       = o0;
  reinterpret_cast<ushort4*>(xn + (size_t)t * DM)[tid + 256] = o1;
}

// ---------------------------------------------------------------------------
// fp32 -> bf16 conversion for BOTH weight matrices in one launch.
// ---------------------------------------------------------------------------
__global__ __launch_bounds__(256) void cvt_both(
    const float* __restrict__ a, unsigned short* __restrict__ oa, int n4a,
    const float* __restrict__ b, unsigned short* __restrict__ ob, int n4b) {
  int i = blockIdx.x * 256 + threadIdx.x;
  const float* src;
  unsigned short* dst;
  int idx;
  if (i < n4a) { src = a; dst = oa; idx = i; }
  else { idx = i - n4a; if (idx >= n4b) return; src = b; dst = ob; }
  float4 v = reinterpret_cast<const float4*>(src)[idx];
  ushort4 o;
  o.x = f2bf(v.x); o.y = f2bf(v.y); o.z = f2bf(v.z); o.w = f2bf(v.w);
  reinterpret_cast<ushort4*>(dst)[idx] = o;
}

// ---------------------------------------------------------------------------
// softmax(-dt) over 4096 elems. Single block.
// ---------------------------------------------------------------------------
__global__ __launch_bounds__(256) void dt_softmax(
    const float* __restrict__ dt, float* __restrict__ w) {
  const int tid = threadIdx.x;
  float e[16];
  float local = 0.f;
  #pragma unroll
  for (int i = 0; i < 16; ++i) {
    float v = __expf(-dt[i * 256 + tid]);
    e[i] = v;
    local += v;
  }
  #pragma unroll
  for (int off = 32; off > 0; off >>= 1) local += __shfl_down(local, off);
  __shared__ float red[4];
  __shared__ float tot;
  if ((tid & 63) == 0) red[tid >> 6] = local;
  __syncthreads();
  if (tid == 0) tot = red[0] + red[1] + red[2] + red[3];
  __syncthreads();
  const float inv = 1.f / tot;
  #pragma unroll
  for (int i = 0; i < 16; ++i) w[i * 256 + tid] = e[i] * inv;
}

__device__ __forceinline__ float actf(float z, float g, float w) {
  float zc = fminf(fmaxf(z, -15.f), 15.f);
  float sz = 1.f / (1.f + __expf(-zc));
  float gc = fminf(fmaxf(g, -15.f), 15.f);
  float sg = 1.f / (1.f + __expf(-gc));
  return z * sz * w * gc * sg;
}

// ===========================================================================
// 8-phase schedule machinery (T2+T3+T4+T5, plain HIP).
// Per K-tile: all 24 frag ds_reads cluster in the K-tile's FIRST phase, so
// its LDS buffer is dead after that phase's trailing barrier; the 4 half-tile
// stages of K-tile kt+2 then legally occupy the following 4 phases.
// vmcnt(6) only at phases 4 and 8 (3 half-tiles = 6 loads in flight).
// ===========================================================================
#define BAR()    __builtin_amdgcn_s_barrier()
#define SCHED0() __builtin_amdgcn_sched_barrier(0)
#define PRIO1()  __builtin_amdgcn_s_setprio(1)
#define PRIO0()  __builtin_amdgcn_s_setprio(0)
#define WAIT_LGKM0() asm volatile("s_waitcnt lgkmcnt(0)" ::: "memory")
#define WAIT_VM6()   asm volatile("s_waitcnt vmcnt(6)" ::: "memory")

#define GLD16(gaddr, laddr) __builtin_amdgcn_global_load_lds(                 \
    (const __attribute__((address_space(1))) void*)(gaddr),                   \
    (__attribute__((address_space(3))) void*)(laddr), 16, 0, 0)

// Stage one 128-row x 64-col bf16 half-tile (16 KB): 2 chunks per thread.
// LDS dest is LINEAR (global_load_lds constraint); the XOR swizzle
// (chunk ^= row&7) is applied on the SOURCE address and undone on ds_read.
#define STAGE(ldsbase, gb, k0) do {                                           \
    GLD16((gb) + sOff  + (k0), &(ldsbase)[tid * 8]);                          \
    GLD16((gb) + sOff2 + (k0), &(ldsbase)[tid * 8 + 4096]);                   \
  } while (0)

// ---------------------------------------------------------------------------
// GEMM1 fused: 256x(128 z + 128 gate) tile, BK=64, 512 threads = 8 waves
// (2M x 4N). Per wave: 128 rows x 32 cols of BOTH z and gate.
// act[t,n] = f(z,g)*dtw[n], z = xn.W_in[n,:], g = xn.W_in[n+DI,:]
// LDS: A 2x32KB + B1 2x16KB + B2 2x16KB = 128 KiB (1 block/CU).
// ---------------------------------------------------------------------------
#define G1_NKT 32   // DM/64
#define G1_NIT 16

__global__ __launch_bounds__(512, 2) void gemm1_fused8(
    const unsigned short* __restrict__ A, const unsigned short* __restrict__ W,
    const float* __restrict__ dtw, unsigned short* __restrict__ act) {
  __shared__ unsigned short lA [2][256 * 64];
  __shared__ unsigned short lB1[2][128 * 64];
  __shared__ unsigned short lB2[2][128 * 64];

  const int tid  = threadIdx.x;
  const int lane = tid & 63;
  const int wmI  = (tid >> 6) >> 2;   // 0..1 -> 128-row half
  const int wnI  = (tid >> 6) & 3;    // 0..3 -> 32-col slice
  const int tM = blockIdx.y * 256;
  const int tN = blockIdx.x * 128;    // z col base; gate at +DI

  const int r0   = lane & 15;
  const int hi4  = lane >> 4;
  const int swz0 = (hi4 ^ (r0 & 7)) << 3;  // shorts, kk=0 chunk
  const int swz1 = swz0 ^ 32;              // kk=32 chunk (^4 in chunk idx)
  const int aRow = (wmI * 128 + r0) * 64;
  const int bRow = (wnI * 32  + r0) * 64;

  // staging constants: thread -> (row, swizzled col) of a 128x64 half-tile
  const int srow = tid >> 3;
  const int scol = ((tid & 7) ^ (srow & 7)) << 3;
  const size_t sOff  = (size_t)srow * DM + scol;
  const size_t sOff2 = sOff + (size_t)64 * DM;

  const unsigned short* Ab    = A + (size_t)tM * DM;
  const unsigned short* Ab128 = Ab + (size_t)128 * DM;
  const unsigned short* B1b   = W + (size_t)tN * DM;
  const unsigned short* B2b   = W + (size_t)(tN + DI) * DM;

  f32x4 accZ[8][2], accG[8][2];
  #pragma unroll
  for (int i = 0; i < 8; ++i)
    #pragma unroll
    for (int j = 0; j < 2; ++j) {
      accZ[i][j] = f32x4{0.f, 0.f, 0.f, 0.f};
      accG[i][j] = f32x4{0.f, 0.f, 0.f, 0.f};
    }
  bf16x8 af[8][2], b1f[2][2], b2f[2][2];

#define G1_READ(b) do {                                                       \
    _Pragma("unroll") for (int i = 0; i < 8; ++i) {                           \
      af[i][0] = *reinterpret_cast<const bf16x8*>(&lA[b][aRow + i*1024 + swz0]); \
      af[i][1] = *reinterpret_cast<const bf16x8*>(&lA[b][aRow + i*1024 + swz1]); \
    }                                                                         \
    _Pragma("unroll") for (int j = 0; j < 2; ++j) {                           \
      b1f[j][0] = *reinterpret_cast<const bf16x8*>(&lB1[b][bRow + j*1024 + swz0]); \
      b1f[j][1] = *reinterpret_cast<const bf16x8*>(&lB1[b][bRow + j*1024 + swz1]); \
      b2f[j][0] = *reinterpret_cast<const bf16x8*>(&lB2[b][bRow + j*1024 + swz0]); \
      b2f[j][1] = *reinterpret_cast<const bf16x8*>(&lB2[b][bRow + j*1024 + swz1]); \
    }                                                                         \
  } while (0)

#define G1_MFMA(kh, ib) do {                                                  \
    _Pragma("unroll") for (int i = 0; i < 4; ++i)                             \
      _Pragma("unroll") for (int j = 0; j < 2; ++j) {                         \
        accZ[ib+i][j] = __builtin_amdgcn_mfma_f32_16x16x32_bf16(              \
            af[ib+i][kh], b1f[j][kh], accZ[ib+i][j], 0, 0, 0);                \
        accG[ib+i][j] = __builtin_amdgcn_mfma_f32_16x16x32_bf16(              \
            af[ib+i][kh], b2f[j][kh], accG[ib+i][j], 0, 0, 0);                \
      }                                                                       \
  } while (0)

  // Prologue: kt0 full (4 halves) + kt1 {A0,A1,B1} -> 14 loads; wait to 6.
  STAGE(lA[0],        Ab,    0);
  STAGE(&lA[0][8192], Ab128, 0);
  STAGE(lB1[0],       B1b,   0);
  STAGE(lB2[0],       B2b,   0);
  STAGE(lA[1],        Ab,    64);
  STAGE(&lA[1][8192], Ab128, 64);
  STAGE(lB1[1],       B1b,   64);
  WAIT_VM6();
  BAR();

  #pragma unroll 1
  for (int t = 0; t < G1_NIT; ++t) {
    const int k1  = (2 * t + 1) * 64;
    const int kt2 = 2 * t + 2;
    const int kt3 = 2 * t + 3;
    const int k2 = (kt2 < G1_NKT ? kt2 : G1_NKT - 1) * 64;  // clamp: dummy
    const int k3 = (kt3 < G1_NKT ? kt3 : G1_NKT - 1) * 64;  // re-stage of tail

    // P1: read kt0 frags (buf0); stage kt1-B2 -> buf1
    G1_READ(0);
    STAGE(lB2[1], B2b, k1);
    BAR(); WAIT_LGKM0(); SCHED0();
    PRIO1(); G1_MFMA(0, 0); PRIO0();
    SCHED0(); BAR();
    // P2: stage kt2-A0 -> buf0 (buf0 reads all retired at P1 barrier)
    STAGE(lA[0], Ab, k2);
    BAR(); SCHED0();
    PRIO1(); G1_MFMA(0, 4); PRIO0();
    SCHED0(); BAR();
    // P3: stage kt2-A1 -> buf0
    STAGE(&lA[0][8192], Ab128, k2);
    BAR(); SCHED0();
    PRIO1(); G1_MFMA(1, 0); PRIO0();
    SCHED0(); BAR();
    // P4: stage kt2-B1 -> buf0; throttle (kt1 fully landed after this)
    STAGE(lB1[0], B1b, k2);
    WAIT_VM6();
    BAR(); SCHED0();
    PRIO1(); G1_MFMA(1, 4); PRIO0();
    SCHED0(); BAR();
    // P5: read kt1 frags (buf1); stage kt2-B2 -> buf0
    G1_READ(1);
    STAGE(lB2[0], B2b, k2);
    BAR(); WAIT_LGKM0(); SCHED0();
    PRIO1(); G1_MFMA(0, 0); PRIO0();
    SCHED0(); BAR();
    // P6: stage kt3-A0 -> buf1
    STAGE(lA[1], Ab, k3);
    BAR(); SCHED0();
    PRIO1(); G1_MFMA(0, 4); PRIO0();
    SCHED0(); BAR();
    // P7: stage kt3-A1 -> buf1
    STAGE(&lA[1][8192], Ab128, k3);
    BAR(); SCHED0();
    PRIO1(); G1_MFMA(1, 0); PRIO0();
    SCHED0(); BAR();
    // P8: stage kt3-B1 -> buf1; throttle (kt2 fully landed after this)
    STAGE(lB1[1], B1b, k3);
    WAIT_VM6();
    BAR(); SCHED0();
    PRIO1(); G1_MFMA(1, 4); PRIO0();
    SCHED0(); BAR();
  }

  // Register epilogue. C/D layout: col = lane&15, row = (lane>>4)*4 + reg.
  const int qr   = hi4 << 2;
  const int colb = tN + wnI * 32 + r0;
  const float w0 = dtw[colb];
  const float w1 = dtw[colb + 16];
  #pragma unroll
  for (int i = 0; i < 8; ++i) {
    #pragma unroll
    for (int r = 0; r < 4; ++r) {
      const size_t base = (size_t)(tM + wmI * 128 + i * 16 + qr + r) * DI + colb;
      act[base]      = f2bf(actf(accZ[i][0][r], accG[i][0][r], w0));
      act[base + 16] = f2bf(actf(accZ[i][1][r], accG[i][1][r], w1));
    }
  }
#undef G1_READ
#undef G1_MFMA
}

// ---------------------------------------------------------------------------
// GEMM2: 256x256 8-phase NT bf16 GEMM with fused residual (fp32 out).
// out[t,d] = sum_e act[t,e]*W_out[d,e] + x[t,d].  K = DI = 4096.
// ---------------------------------------------------------------------------
#define G2_NKT 64   // DI/64
#define G2_NIT 32

__global__ __launch_bounds__(512, 2) void gemm2_res8(
    const unsigned short* __restrict__ A, const unsigned short* __restrict__ Bm,
    float* __restrict__ out, const float* __restrict__ ident) {
  __shared__ unsigned short lA[2][256 * 64];
  __shared__ unsigned short lB[2][256 * 64];

  const int tid  = threadIdx.x;
  const int lane = tid & 63;
  const int wmI  = (tid >> 6) >> 2;   // 0..1
  const int wnI  = (tid >> 6) & 3;    // 0..3 -> 64-col slice
  const int tM = blockIdx.y * 256;
  const int tN = blockIdx.x * 256;

  const int r0   = lane & 15;
  const int hi4  = lane >> 4;
  const int swz0 = (hi4 ^ (r0 & 7)) << 3;
  const int swz1 = swz0 ^ 32;
  const int aRow = (wmI * 128 + r0) * 64;
  const int bRow = (wnI * 64  + r0) * 64;

  const int srow = tid >> 3;
  const int scol = ((tid & 7) ^ (srow & 7)) << 3;
  const size_t sOff  = (size_t)srow * DI + scol;
  const size_t sOff2 = sOff + (size_t)64 * DI;

  const unsigned short* Ab    = A + (size_t)tM * DI;
  const unsigned short* Ab128 = Ab + (size_t)128 * DI;
  const unsigned short* Bb    = Bm + (size_t)tN * DI;
  const unsigned short* Bb128 = Bb + (size_t)128 * DI;

  f32x4 acc[8][4];
  #pragma unroll
  for (int i = 0; i < 8; ++i)
    #pragma unroll
    for (int j = 0; j < 4; ++j) acc[i][j] = f32x4{0.f, 0.f, 0.f, 0.f};
  bf16x8 af[8][2], bfr[4][2];

#define G2_READ(b) do {                                                       \
    _Pragma("unroll") for (int i = 0; i < 8; ++i) {                           \
      af[i][0] = *reinterpret_cast<const bf16x8*>(&lA[b][aRow + i*1024 + swz0]); \
      af[i][1] = *reinterpret_cast<const bf16x8*>(&lA[b][aRow + i*1024 + swz1]); \
    }                                                                         \
    _Pragma("unroll") for (int j = 0; j < 4; ++j) {                           \
      bfr[j][0] = *reinterpret_cast<const bf16x8*>(&lB[b][bRow + j*1024 + swz0]); \
      bfr[j][1] = *reinterpret_cast<const bf16x8*>(&lB[b][bRow + j*1024 + swz1]); \
    }                                                                         \
  } while (0)

#define G2_MFMA(kh, ib) do {                                                  \
    _Pragma("unroll") for (int i = 0; i < 4; ++i)                             \
      _Pragma("unroll") for (int j = 0; j < 4; ++j)                           \
        acc[ib+i][j] = __builtin_amdgcn_mfma_f32_16x16x32_bf16(               \
            af[ib+i][kh], bfr[j][kh], acc[ib+i][j], 0, 0, 0);                 \
  } while (0)

  // Prologue: kt0 full + kt1 {A0,A1,B0}
  STAGE(lA[0],        Ab,    0);
  STAGE(&lA[0][8192], Ab128, 0);
  STAGE(lB[0],        Bb,    0);
  STAGE(&lB[0][8192], Bb128, 0);
  STAGE(lA[1],        Ab,    64);
  STAGE(&lA[1][8192], Ab128, 64);
  STAGE(lB[1],        Bb,    64);
  WAIT_VM6();
  BAR();

  #pragma unroll 1
  for (int t = 0; t < G2_NIT; ++t) {
    const int k1  = (2 * t + 1) * 64;
    const int kt2 = 2 * t + 2;
    const int kt3 = 2 * t + 3;
    const int k2 = (kt2 < G2_NKT ? kt2 : G2_NKT - 1) * 64;
    const int k3 = (kt3 < G2_NKT ? kt3 : G2_NKT - 1) * 64;

    // P1
    G2_READ(0);
    STAGE(&lB[1][8192], Bb128, k1);
    BAR(); WAIT_LGKM0(); SCHED0();
    PRIO1(); G2_MFMA(0, 0); PRIO0();
    SCHED0(); BAR();
    // P2
    STAGE(lA[0], Ab, k2);
    BAR(); SCHED0();
    PRIO1(); G2_MFMA(0, 4); PRIO0();
    SCHED0(); BAR();
    // P3
    STAGE(&lA[0][8192], Ab128, k2);
    BAR(); SCHED0();
    PRIO1(); G2_MFMA(1, 0); PRIO0();
    SCHED0(); BAR();
    // P4
    STAGE(lB[0], Bb, k2);
    WAIT_VM6();
    BAR(); SCHED0();
    PRIO1(); G2_MFMA(1, 4); PRIO0();
    SCHED0(); BAR();
    // P5
    G2_READ(1);
    STAGE(&lB[0][8192], Bb128, k2);
    BAR(); WAIT_LGKM0(); SCHED0();
    PRIO1(); G2_MFMA(0, 0); PRIO0();
    SCHED0(); BAR();
    // P6
    STAGE(lA[1], Ab, k3);
    BAR(); SCHED0();
    PRIO1(); G2_MFMA(0, 4); PRIO0();
    SCHED0(); BAR();
    // P7
    STAGE(&lA[1][8192], Ab128, k3);
    BAR(); SCHED0();
    PRIO1(); G2_MFMA(1, 0); PRIO0();
    SCHED0(); BAR();
    // P8
    STAGE(lB[1], Bb, k3);
    WAIT_VM6();
    BAR(); SCHED0();
    PRIO1(); G2_MFMA(1, 4); PRIO0();
    SCHED0(); BAR();
  }

  const int qr   = hi4 << 2;
  const int colb = tN + wnI * 64 + r0;
  #pragma unroll
  for (int i = 0; i < 8; ++i) {
    #pragma unroll
    for (int r = 0; r < 4; ++r) {
      const size_t rowoff = (size_t)(tM + wmI * 128 + i * 16 + qr + r) * DM;
      #pragma unroll
      for (int j = 0; j < 4; ++j) {
        const size_t idx = rowoff + colb + j * 16;
        out[idx] = acc[i][j][r] + ident[idx];
      }
    }
  }
#undef G2_READ
#undef G2_MFMA
}

// ---------------------------------------------------------------------------
// Workspace layout (~160 MB):
//   [0, 32MB)     xn bf16 [8192][2048]
//   [32, 64MB)    W_in bf16 [8192][2048]
//   [64, 80MB)    W_out bf16 [2048][4096]
//   [80MB, +16K)  dt_weights fp32 [4096]
//   [96, 160MB)   act bf16 [8192][4096]
// ---------------------------------------------------------------------------
extern "C" void kernel_launch(void* const* d_in, const int* in_sizes, int n_in,
                              void* d_out, int out_size, void* d_ws, size_t ws_size,
                              hipStream_t stream) {
  const float* x     = (const float*)d_in[0];
  const float* gamma = (const float*)d_in[1];
  const float* beta  = (const float*)d_in[2];
  const float* W_in  = (const float*)d_in[3];
  const float* W_out = (const float*)d_in[4];
  const float* dt    = (const float*)d_in[5];
  float* out = (float*)d_out;

  char* ws = (char*)d_ws;
  unsigned short* xn     = (unsigned short*)(ws);
  unsigned short* win_b  = (unsigned short*)(ws + ((size_t)32 << 20));
  unsigned short* wout_b = (unsigned short*)(ws + ((size_t)64 << 20));
  float*          dtw    = (float*)(ws + ((size_t)80 << 20));
  unsigned short* act    = (unsigned short*)(ws + ((size_t)96 << 20));

  const int n4_in  = TWO_DI * DM / 4;
  const int n4_out = DM * DI / 4;

  ln_kernel<<<T_TOK, 256, 0, stream>>>(x, gamma, beta, xn);
  cvt_both<<<(n4_in + n4_out + 255) / 256, 256, 0, stream>>>(
      W_in, win_b, n4_in, W_out, wout_b, n4_out);
  dt_softmax<<<1, 256, 0, stream>>>(dt, dtw);

  // GEMM1 + gated activation fused, 8-phase: act[t,e], e in [0,DI)
  gemm1_fused8<<<dim3(DI / 128, T_TOK / 256), 512, 0, stream>>>(
      xn, win_b, dtw, act);

  // GEMM2 8-phase: out[t,d] = sum_e act[t,e] * W_out[d,e] + x[t,d]
  gemm2_res8<<<dim3(DM / 256, T_TOK / 256), 512, 0, stream>>>(
      act, wout_b, out, x);
}

// Round 4
// 574.508 us; speedup vs baseline: 1.0434x; 1.0434x over previous
//
#include <hip/hip_runtime.h>
#include <cstdint>
#include <cstddef>

// Problem constants
#define T_TOK 8192    // B*S tokens
#define DM    2048    // d_model
#define DI    4096    // d_inner
#define TWO_DI 8192

typedef __attribute__((ext_vector_type(8))) short bf16x8;
typedef __attribute__((ext_vector_type(4))) float f32x4;

__device__ __forceinline__ unsigned short f2bf(float f) {
  union { float f; unsigned u; } c; c.f = f;
  unsigned u = c.u;
  unsigned r = (u + 0x7fffu + ((u >> 16) & 1u)) >> 16;  // RNE
  return (unsigned short)r;
}

// ---------------------------------------------------------------------------
// LayerNorm over last dim (2048) + cast to bf16. One block per token.
// ---------------------------------------------------------------------------
__global__ __launch_bounds__(256) void ln_kernel(
    const float* __restrict__ x, const float* __restrict__ gamma,
    const float* __restrict__ beta, unsigned short* __restrict__ xn) {
  const int t = blockIdx.x;
  const int tid = threadIdx.x;
  const float* row = x + (size_t)t * DM;
  float4 v0 = reinterpret_cast<const float4*>(row)[tid];
  float4 v1 = reinterpret_cast<const float4*>(row)[tid + 256];
  float s  = v0.x + v0.y + v0.z + v0.w + v1.x + v1.y + v1.z + v1.w;
  float ss = v0.x*v0.x + v0.y*v0.y + v0.z*v0.z + v0.w*v0.w
           + v1.x*v1.x + v1.y*v1.y + v1.z*v1.z + v1.w*v1.w;
  #pragma unroll
  for (int off = 32; off > 0; off >>= 1) {
    s  += __shfl_down(s, off);
    ss += __shfl_down(ss, off);
  }
  __shared__ float red[8];
  __shared__ float mu_s, inv_s;
  if ((tid & 63) == 0) { red[tid >> 6] = s; red[4 + (tid >> 6)] = ss; }
  __syncthreads();
  if (tid == 0) {
    float S  = red[0] + red[1] + red[2] + red[3];
    float SS = red[4] + red[5] + red[6] + red[7];
    float mu  = S * (1.0f / DM);
    float var = SS * (1.0f / DM) - mu * mu;
    mu_s = mu;
    inv_s = rsqrtf(var + 1e-5f);
  }
  __syncthreads();
  const float mu = mu_s, inv = inv_s;
  float4 g0 = reinterpret_cast<const float4*>(gamma)[tid];
  float4 b0 = reinterpret_cast<const float4*>(beta)[tid];
  float4 g1 = reinterpret_cast<const float4*>(gamma)[tid + 256];
  float4 b1 = reinterpret_cast<const float4*>(beta)[tid + 256];
  ushort4 o0, o1;
  o0.x = f2bf((v0.x - mu) * inv * g0.x + b0.x);
  o0.y = f2bf((v0.y - mu) * inv * g0.y + b0.y);
  o0.z = f2bf((v0.z - mu) * inv * g0.z + b0.z);
  o0.w = f2bf((v0.w - mu) * inv * g0.w + b0.w);
  o1.x = f2bf((v1.x - mu) * inv * g1.x + b1.x);
  o1.y = f2bf((v1.y - mu) * inv * g1.y + b1.y);
  o1.z = f2bf((v1.z - mu) * inv * g1.z + b1.z);
  o1.w = f2bf((v1.w - mu) * inv * g1.w + b1.w);
  reinterpret_cast<ushort4*>(xn + (size_t)t * DM)[tid]       = o0;
  reinterpret_cast<ushort4*>(xn + (size_t)t * DM)[tid + 256] = o1;
}

// ---------------------------------------------------------------------------
// fp32 -> bf16 conversion for BOTH weight matrices in one launch.
// ---------------------------------------------------------------------------
__global__ __launch_bounds__(256) void cvt_both(
    const float* __restrict__ a, unsigned short* __restrict__ oa, int n4a,
    const float* __restrict__ b, unsigned short* __restrict__ ob, int n4b) {
  int i = blockIdx.x * 256 + threadIdx.x;
  const float* src;
  unsigned short* dst;
  int idx;
  if (i < n4a) { src = a; dst = oa; idx = i; }
  else { idx = i - n4a; if (idx >= n4b) return; src = b; dst = ob; }
  float4 v = reinterpret_cast<const float4*>(src)[idx];
  ushort4 o;
  o.x = f2bf(v.x); o.y = f2bf(v.y); o.z = f2bf(v.z); o.w = f2bf(v.w);
  reinterpret_cast<ushort4*>(dst)[idx] = o;
}

// ---------------------------------------------------------------------------
// softmax(-dt) over 4096 elems. Single block.
// ---------------------------------------------------------------------------
__global__ __launch_bounds__(256) void dt_softmax(
    const float* __restrict__ dt, float* __restrict__ w) {
  const int tid = threadIdx.x;
  float e[16];
  float local = 0.f;
  #pragma unroll
  for (int i = 0; i < 16; ++i) {
    float v = __expf(-dt[i * 256 + tid]);
    e[i] = v;
    local += v;
  }
  #pragma unroll
  for (int off = 32; off > 0; off >>= 1) local += __shfl_down(local, off);
  __shared__ float red[4];
  __shared__ float tot;
  if ((tid & 63) == 0) red[tid >> 6] = local;
  __syncthreads();
  if (tid == 0) tot = red[0] + red[1] + red[2] + red[3];
  __syncthreads();
  const float inv = 1.f / tot;
  #pragma unroll
  for (int i = 0; i < 16; ++i) w[i * 256 + tid] = e[i] * inv;
}

__device__ __forceinline__ float actf(float z, float g, float w) {
  float zc = fminf(fmaxf(z, -15.f), 15.f);
  float sz = 1.f / (1.f + __expf(-zc));
  float gc = fminf(fmaxf(g, -15.f), 15.f);
  float sg = 1.f / (1.f + __expf(-gc));
  return z * sz * w * gc * sg;
}

// ===========================================================================
// 8-phase schedule (m201-faithful): EVERY phase = {4-8 ds_reads for THIS
// phase's MFMA quadrant; optional 4-load stage burst; BAR; lgkmcnt(0);
// sched_barrier; setprio(1); 16 MFMA; setprio(0); sched_barrier; BAR}.
// Stage bursts: P1 = kt+1 A-pair, P4 = kt+2 B-pair (+vmcnt(4)),
// P5 = kt+2 A-pair, P8 = kt+3 B-pair (+vmcnt(4)).
// vmcnt(4) at P4 proves kt+1 A/B landed before P5; at P8 proves kt+2
// landed before next P1 (only own burst may remain outstanding).
// Buffer-free: A-halves last read in p4 of their K-tile (restage >= p5),
// B-halves in p3 (restage >= p4); all stage issues sit after the ordering
// barrier, so DMA writes cannot race the frag reads.
// ===========================================================================
#define BAR()    __builtin_amdgcn_s_barrier()
#define SCHED0() __builtin_amdgcn_sched_barrier(0)
#define PRIO1()  __builtin_amdgcn_s_setprio(1)
#define PRIO0()  __builtin_amdgcn_s_setprio(0)
#define WAIT_LGKM0() asm volatile("s_waitcnt lgkmcnt(0)" ::: "memory")
#define WAIT_VM4()   asm volatile("s_waitcnt vmcnt(4)" ::: "memory")

#define GLD16(gaddr, laddr) __builtin_amdgcn_global_load_lds(                 \
    (const __attribute__((address_space(1))) void*)(gaddr),                   \
    (__attribute__((address_space(3))) void*)(laddr), 16, 0, 0)

// Stage one 128-row x 64-col bf16 half-tile (16 KB): 2 chunks per thread.
// LDS dest is LINEAR (global_load_lds constraint); the XOR swizzle
// (chunk ^= row&7) is applied on the SOURCE address and undone on ds_read.
#define STAGE(ldsbase, gb, k0) do {                                           \
    GLD16((gb) + sOff  + (k0), &(ldsbase)[tid * 8]);                          \
    GLD16((gb) + sOff2 + (k0), &(ldsbase)[tid * 8 + 4096]);                   \
  } while (0)

// ---------------------------------------------------------------------------
// GEMM1 fused: 256x(128 z + 128 gate) tile, BK=64, 512 threads = 8 waves
// (2M x 4N). Per wave: 128 rows x 32 cols of BOTH z and gate.
// act[t,n] = f(z,g)*dtw[n], z = xn.W_in[n,:], g = xn.W_in[n+DI,:]
// LDS: A 2x32KB + B1 2x16KB + B2 2x16KB = 128 KiB (1 block/CU).
// ---------------------------------------------------------------------------
#define G1_NKT 32   // DM/64
#define G1_NIT 16

__global__ __launch_bounds__(512, 2) void gemm1_fused8(
    const unsigned short* __restrict__ A, const unsigned short* __restrict__ W,
    const float* __restrict__ dtw, unsigned short* __restrict__ act) {
  __shared__ unsigned short lA [2][256 * 64];
  __shared__ unsigned short lB1[2][128 * 64];
  __shared__ unsigned short lB2[2][128 * 64];

  const int tid  = threadIdx.x;
  const int lane = tid & 63;
  const int wmI  = (tid >> 6) >> 2;   // 0..1 -> 128-row half
  const int wnI  = (tid >> 6) & 3;    // 0..3 -> 32-col slice
  const int tM = blockIdx.y * 256;
  const int tN = blockIdx.x * 128;    // z col base; gate at +DI

  const int r0   = lane & 15;
  const int hi4  = lane >> 4;
  const int swz0 = (hi4 ^ (r0 & 7)) << 3;  // shorts, kk=0 chunk
  const int swz1 = swz0 ^ 32;              // kk=32 chunk
  const int aRow = (wmI * 128 + r0) * 64;
  const int bRow = (wnI * 32  + r0) * 64;

  // staging constants: thread -> (row, swizzled col) of a 128x64 half-tile
  const int srow = tid >> 3;
  const int scol = ((tid & 7) ^ (srow & 7)) << 3;
  const size_t sOff  = (size_t)srow * DM + scol;
  const size_t sOff2 = sOff + (size_t)64 * DM;

  const unsigned short* Ab    = A + (size_t)tM * DM;
  const unsigned short* Ab128 = Ab + (size_t)128 * DM;
  const unsigned short* B1b   = W + (size_t)tN * DM;
  const unsigned short* B2b   = W + (size_t)(tN + DI) * DM;

  f32x4 accZ[8][2], accG[8][2];
  #pragma unroll
  for (int i = 0; i < 8; ++i)
    #pragma unroll
    for (int j = 0; j < 2; ++j) {
      accZ[i][j] = f32x4{0.f, 0.f, 0.f, 0.f};
      accG[i][j] = f32x4{0.f, 0.f, 0.f, 0.f};
    }
  bf16x8 aR[4], bR1[2], bR2[2];

#define G1_LDA(b, idx, sw) do {                                               \
    _Pragma("unroll") for (int i = 0; i < 4; ++i)                             \
      aR[i] = *reinterpret_cast<const bf16x8*>(                               \
          &lA[b][aRow + ((idx) + i) * 1024 + (sw)]);                          \
  } while (0)
#define G1_LDB(b, sw) do {                                                    \
    _Pragma("unroll") for (int j = 0; j < 2; ++j) {                           \
      bR1[j] = *reinterpret_cast<const bf16x8*>(&lB1[b][bRow + j*1024 + (sw)]); \
      bR2[j] = *reinterpret_cast<const bf16x8*>(&lB2[b][bRow + j*1024 + (sw)]); \
    }                                                                         \
  } while (0)
#define G1_MFMA16(ib) do {                                                    \
    _Pragma("unroll") for (int i = 0; i < 4; ++i)                             \
      _Pragma("unroll") for (int j = 0; j < 2; ++j) {                         \
        accZ[(ib)+i][j] = __builtin_amdgcn_mfma_f32_16x16x32_bf16(            \
            aR[i], bR1[j], accZ[(ib)+i][j], 0, 0, 0);                         \
        accG[(ib)+i][j] = __builtin_amdgcn_mfma_f32_16x16x32_bf16(            \
            aR[i], bR2[j], accG[(ib)+i][j], 0, 0, 0);                         \
      }                                                                       \
  } while (0)
#define G1_TAIL() do {                                                        \
    BAR(); WAIT_LGKM0(); SCHED0();                                            \
  } while (0)
#define G1_MF(ib) do {                                                        \
    PRIO1(); G1_MFMA16(ib); PRIO0(); SCHED0(); BAR();                         \
  } while (0)

  // Prologue: kt0 {A0,A1,B1,B2} + kt1 {B1,B2}; vmcnt(4) -> kt0 landed.
  STAGE(lA[0],        Ab,    0);
  STAGE(&lA[0][8192], Ab128, 0);
  STAGE(lB1[0],       B1b,   0);
  STAGE(lB2[0],       B2b,   0);
  STAGE(lB1[1],       B1b,   64);
  STAGE(lB2[1],       B2b,   64);
  WAIT_VM4();
  BAR();

  #pragma unroll 1
  for (int t = 0; t < G1_NIT; ++t) {
    const int k1  = (2 * t + 1) * 64;
    const int kt2 = 2 * t + 2;
    const int kt3 = 2 * t + 3;
    const int k2 = (kt2 < G1_NKT ? kt2 : G1_NKT - 1) * 64;  // clamp: dummy
    const int k3 = (kt3 < G1_NKT ? kt3 : G1_NKT - 1) * 64;  // re-stage (safe)

    // ---- kt0 on buf0 ----
    // P1: (kh0, ib0); stage kt1-A pair -> buf1 (buf1-A free since prev P8)
    G1_LDA(0, 0, swz0); G1_LDB(0, swz0);
    STAGE(lA[1], Ab, k1); STAGE(&lA[1][8192], Ab128, k1);
    G1_TAIL(); G1_MF(0);
    // P2: (kh0, ib4)
    G1_LDA(0, 4, swz0);
    G1_TAIL(); G1_MF(4);
    // P3: (kh1, ib0)
    G1_LDA(0, 0, swz1); G1_LDB(0, swz1);
    G1_TAIL(); G1_MF(0);
    // P4: (kh1, ib4); stage kt2-B pair -> buf0-B (free after P3); vmcnt(4)
    G1_LDA(0, 4, swz1);
    STAGE(lB1[0], B1b, k2); STAGE(lB2[0], B2b, k2);
    WAIT_VM4();
    G1_TAIL(); G1_MF(4);

    // ---- kt1 on buf1 ----
    // P5: (kh0, ib0); stage kt2-A pair -> buf0-A (free after P4)
    G1_LDA(1, 0, swz0); G1_LDB(1, swz0);
    STAGE(lA[0], Ab, k2); STAGE(&lA[0][8192], Ab128, k2);
    G1_TAIL(); G1_MF(0);
    // P6: (kh0, ib4)
    G1_LDA(1, 4, swz0);
    G1_TAIL(); G1_MF(4);
    // P7: (kh1, ib0)
    G1_LDA(1, 0, swz1); G1_LDB(1, swz1);
    G1_TAIL(); G1_MF(0);
    // P8: (kh1, ib4); stage kt3-B pair -> buf1-B (free after P7); vmcnt(4)
    G1_LDA(1, 4, swz1);
    STAGE(lB1[1], B1b, k3); STAGE(lB2[1], B2b, k3);
    WAIT_VM4();
    G1_TAIL(); G1_MF(4);
  }

  // Register epilogue. C/D layout: col = lane&15, row = (lane>>4)*4 + reg.
  const int qr   = hi4 << 2;
  const int colb = tN + wnI * 32 + r0;
  const float w0 = dtw[colb];
  const float w1 = dtw[colb + 16];
  #pragma unroll
  for (int i = 0; i < 8; ++i) {
    #pragma unroll
    for (int r = 0; r < 4; ++r) {
      const size_t base = (size_t)(tM + wmI * 128 + i * 16 + qr + r) * DI + colb;
      act[base]      = f2bf(actf(accZ[i][0][r], accG[i][0][r], w0));
      act[base + 16] = f2bf(actf(accZ[i][1][r], accG[i][1][r], w1));
    }
  }
#undef G1_LDA
#undef G1_LDB
#undef G1_MFMA16
#undef G1_TAIL
#undef G1_MF
}

// ---------------------------------------------------------------------------
// GEMM2: 256x256 8-phase NT bf16 GEMM with fused residual (fp32 out).
// out[t,d] = sum_e act[t,e]*W_out[d,e] + x[t,d].  K = DI = 4096.
// ---------------------------------------------------------------------------
#define G2_NKT 64   // DI/64
#define G2_NIT 32

__global__ __launch_bounds__(512, 2) void gemm2_res8(
    const unsigned short* __restrict__ A, const unsigned short* __restrict__ Bm,
    float* __restrict__ out, const float* __restrict__ ident) {
  __shared__ unsigned short lA[2][256 * 64];
  __shared__ unsigned short lB[2][256 * 64];

  const int tid  = threadIdx.x;
  const int lane = tid & 63;
  const int wmI  = (tid >> 6) >> 2;   // 0..1
  const int wnI  = (tid >> 6) & 3;    // 0..3 -> 64-col slice
  const int tM = blockIdx.y * 256;
  const int tN = blockIdx.x * 256;

  const int r0   = lane & 15;
  const int hi4  = lane >> 4;
  const int swz0 = (hi4 ^ (r0 & 7)) << 3;
  const int swz1 = swz0 ^ 32;
  const int aRow = (wmI * 128 + r0) * 64;
  const int bRow = (wnI * 64  + r0) * 64;

  const int srow = tid >> 3;
  const int scol = ((tid & 7) ^ (srow & 7)) << 3;
  const size_t sOff  = (size_t)srow * DI + scol;
  const size_t sOff2 = sOff + (size_t)64 * DI;

  const unsigned short* Ab    = A + (size_t)tM * DI;
  const unsigned short* Ab128 = Ab + (size_t)128 * DI;
  const unsigned short* Bb    = Bm + (size_t)tN * DI;
  const unsigned short* Bb128 = Bb + (size_t)128 * DI;

  f32x4 acc[8][4];
  #pragma unroll
  for (int i = 0; i < 8; ++i)
    #pragma unroll
    for (int j = 0; j < 4; ++j) acc[i][j] = f32x4{0.f, 0.f, 0.f, 0.f};
  bf16x8 aR[4], bR[4];

#define G2_LDA(b, idx, sw) do {                                               \
    _Pragma("unroll") for (int i = 0; i < 4; ++i)                             \
      aR[i] = *reinterpret_cast<const bf16x8*>(                               \
          &lA[b][aRow + ((idx) + i) * 1024 + (sw)]);                          \
  } while (0)
#define G2_LDB(b, sw) do {                                                    \
    _Pragma("unroll") for (int j = 0; j < 4; ++j)                             \
      bR[j] = *reinterpret_cast<const bf16x8*>(&lB[b][bRow + j*1024 + (sw)]); \
  } while (0)
#define G2_MFMA16(ib) do {                                                    \
    _Pragma("unroll") for (int i = 0; i < 4; ++i)                             \
      _Pragma("unroll") for (int j = 0; j < 4; ++j)                           \
        acc[(ib)+i][j] = __builtin_amdgcn_mfma_f32_16x16x32_bf16(             \
            aR[i], bR[j], acc[(ib)+i][j], 0, 0, 0);                           \
  } while (0)
#define G2_TAIL() do {                                                        \
    BAR(); WAIT_LGKM0(); SCHED0();                                            \
  } while (0)
#define G2_MF(ib) do {                                                        \
    PRIO1(); G2_MFMA16(ib); PRIO0(); SCHED0(); BAR();                         \
  } while (0)

  // Prologue: kt0 {A0,A1,B0,B1} + kt1 {B0,B1}; vmcnt(4) -> kt0 landed.
  STAGE(lA[0],        Ab,    0);
  STAGE(&lA[0][8192], Ab128, 0);
  STAGE(lB[0],        Bb,    0);
  STAGE(&lB[0][8192], Bb128, 0);
  STAGE(lB[1],        Bb,    64);
  STAGE(&lB[1][8192], Bb128, 64);
  WAIT_VM4();
  BAR();

  #pragma unroll 1
  for (int t = 0; t < G2_NIT; ++t) {
    const int k1  = (2 * t + 1) * 64;
    const int kt2 = 2 * t + 2;
    const int kt3 = 2 * t + 3;
    const int k2 = (kt2 < G2_NKT ? kt2 : G2_NKT - 1) * 64;
    const int k3 = (kt3 < G2_NKT ? kt3 : G2_NKT - 1) * 64;

    // ---- kt0 on buf0 ----
    // P1: (kh0, ib0); stage kt1-A pair -> buf1-A
    G2_LDA(0, 0, swz0); G2_LDB(0, swz0);
    STAGE(lA[1], Ab, k1); STAGE(&lA[1][8192], Ab128, k1);
    G2_TAIL(); G2_MF(0);
    // P2: (kh0, ib4)
    G2_LDA(0, 4, swz0);
    G2_TAIL(); G2_MF(4);
    // P3: (kh1, ib0)
    G2_LDA(0, 0, swz1); G2_LDB(0, swz1);
    G2_TAIL(); G2_MF(0);
    // P4: (kh1, ib4); stage kt2-B pair -> buf0-B; vmcnt(4)
    G2_LDA(0, 4, swz1);
    STAGE(lB[0], Bb, k2); STAGE(&lB[0][8192], Bb128, k2);
    WAIT_VM4();
    G2_TAIL(); G2_MF(4);

    // ---- kt1 on buf1 ----
    // P5: (kh0, ib0); stage kt2-A pair -> buf0-A
    G2_LDA(1, 0, swz0); G2_LDB(1, swz0);
    STAGE(lA[0], Ab, k2); STAGE(&lA[0][8192], Ab128, k2);
    G2_TAIL(); G2_MF(0);
    // P6: (kh0, ib4)
    G2_LDA(1, 4, swz0);
    G2_TAIL(); G2_MF(4);
    // P7: (kh1, ib0)
    G2_LDA(1, 0, swz1); G2_LDB(1, swz1);
    G2_TAIL(); G2_MF(0);
    // P8: (kh1, ib4); stage kt3-B pair -> buf1-B; vmcnt(4)
    G2_LDA(1, 4, swz1);
    STAGE(lB[1], Bb, k3); STAGE(&lB[1][8192], Bb128, k3);
    WAIT_VM4();
    G2_TAIL(); G2_MF(4);
  }

  const int qr   = hi4 << 2;
  const int colb = tN + wnI * 64 + r0;
  #pragma unroll
  for (int i = 0; i < 8; ++i) {
    #pragma unroll
    for (int r = 0; r < 4; ++r) {
      const size_t rowoff = (size_t)(tM + wmI * 128 + i * 16 + qr + r) * DM;
      #pragma unroll
      for (int j = 0; j < 4; ++j) {
        const size_t idx = rowoff + colb + j * 16;
        out[idx] = acc[i][j][r] + ident[idx];
      }
    }
  }
#undef G2_LDA
#undef G2_LDB
#undef G2_MFMA16
#undef G2_TAIL
#undef G2_MF
}

// ---------------------------------------------------------------------------
// Workspace layout (~160 MB):
//   [0, 32MB)     xn bf16 [8192][2048]
//   [32, 64MB)    W_in bf16 [8192][2048]
//   [64, 80MB)    W_out bf16 [2048][4096]
//   [80MB, +16K)  dt_weights fp32 [4096]
//   [96, 160MB)   act bf16 [8192][4096]
// ---------------------------------------------------------------------------
extern "C" void kernel_launch(void* const* d_in, const int* in_sizes, int n_in,
                              void* d_out, int out_size, void* d_ws, size_t ws_size,
                              hipStream_t stream) {
  const float* x     = (const float*)d_in[0];
  const float* gamma = (const float*)d_in[1];
  const float* beta  = (const float*)d_in[2];
  const float* W_in  = (const float*)d_in[3];
  const float* W_out = (const float*)d_in[4];
  const float* dt    = (const float*)d_in[5];
  float* out = (float*)d_out;

  char* ws = (char*)d_ws;
  unsigned short* xn     = (unsigned short*)(ws);
  unsigned short* win_b  = (unsigned short*)(ws + ((size_t)32 << 20));
  unsigned short* wout_b = (unsigned short*)(ws + ((size_t)64 << 20));
  float*          dtw    = (float*)(ws + ((size_t)80 << 20));
  unsigned short* act    = (unsigned short*)(ws + ((size_t)96 << 20));

  const int n4_in  = TWO_DI * DM / 4;
  const int n4_out = DM * DI / 4;

  ln_kernel<<<T_TOK, 256, 0, stream>>>(x, gamma, beta, xn);
  cvt_both<<<(n4_in + n4_out + 255) / 256, 256, 0, stream>>>(
      W_in, win_b, n4_in, W_out, wout_b, n4_out);
  dt_softmax<<<1, 256, 0, stream>>>(dt, dtw);

  // GEMM1 + gated activation fused, 8-phase: act[t,e], e in [0,DI)
  gemm1_fused8<<<dim3(DI / 128, T_TOK / 256), 512, 0, stream>>>(
      xn, win_b, dtw, act);

  // GEMM2 8-phase: out[t,d] = sum_e act[t,e] * W_out[d,e] + x[t,d]
  gemm2_res8<<<dim3(DM / 256, T_TOK / 256), 512, 0, stream>>>(
      act, wout_b, out, x);
}